// Round 17
// baseline (149.397 us; speedup 1.0000x reference)
//
#include <hip/hip_runtime.h>
#include <hip/hip_bf16.h>
#include <math.h>

namespace {

constexpr int kB = 2, kT = 2048, kC = 1024, kNH = 16, kHS = 64;
constexpr int kM = kB * kT;                 // 4096 rows
constexpr int kChunk = 32, kNChunk = kT / kChunk;   // decay scan chunking
constexpr float kES = 10.0f;                // EXP_SCALING
constexpr float kKSM = 11.090339630053647f; // log(2^16 - 1)
// |q.k| <= |q||k| = e^2 = 7.389 (k rows unit-L2 scaled by exp(1)).
// kbf additionally carries sqrt(log2 e) on both q and k, so MFMA scores are
// log2e*(q.k); with C-init = -7.5*log2e, p = exp2(s) = exp(q.k - 7.5) exactly.
constexpr float kSqrtLog2e = 1.2011224087864498f;
constexpr float kC4 = -10.820212806667226f;  // -7.5 * log2(e)

typedef __attribute__((ext_vector_type(8))) short bf16x8;
typedef __attribute__((ext_vector_type(4))) float f32x4;
typedef __attribute__((ext_vector_type(8))) unsigned short us8;

__device__ __forceinline__ size_t rowoff(int b, int t) {
  return ((size_t)b * kT + t) * kC;
}

// fp32 -> bf16 bits, round-to-nearest-even
__device__ __forceinline__ unsigned short f2bf(float f) {
  unsigned int u = __float_as_uint(f);
  u += 0x7fffu + ((u >> 16) & 1u);
  return (unsigned short)(u >> 16);
}
__device__ __forceinline__ float bf2f(unsigned short h) {
  return __uint_as_float((unsigned int)h << 16);
}

__device__ __forceinline__ f32x4 mfma16(bf16x8 a, bf16x8 b, f32x4 c) {
  return __builtin_amdgcn_mfma_f32_16x16x32_bf16(a, b, c, 0, 0, 0);
}

// pack two f32 -> dword of 2 bf16 (lo = a, hi = b)
__device__ __forceinline__ int cvtpk(float a, float b) {
  int r;
  asm("v_cvt_pk_bf16_f32 %0, %1, %2" : "=v"(r) : "v"(a), "v"(b));
  return r;
}

// async global->LDS, 16B per lane. LDS dest = wave-uniform base + lane*16.
__device__ __forceinline__ void gload16(const unsigned short* g, unsigned short* l) {
  __builtin_amdgcn_global_load_lds(
      (const __attribute__((address_space(1))) unsigned int*)g,
      (__attribute__((address_space(3))) unsigned int*)l, 16, 0, 0);
}

// swizzled fragment read: 8 shorts of (row, 16B-chunk cg) in a [*][64]-short
// linear tile where chunk slots are XOR'd by (row&7).
__device__ __forceinline__ bf16x8 ldsfrag(const unsigned short* arr, int row, int cg) {
  return *(const bf16x8*)&arr[row * 64 + ((cg ^ (row & 7)) << 3)];
}

// All input splits in one dispatch (all plain bf16):
//   blocks [0,4096)      : x -> Xhi
//   blocks [4096,5120)   : Wk -> Wkh
//   blocks [5120,6144)   : Wv -> Wvh
//   blocks [6144,7168)   : Wc -> Wch
__global__ __launch_bounds__(256)
void split_all(const float* __restrict__ x, unsigned short* __restrict__ Xhi,
               const float* __restrict__ Wk, unsigned short* __restrict__ Wkh,
               const float* __restrict__ Wv, unsigned short* __restrict__ Wvh,
               const float* __restrict__ Wc, unsigned short* __restrict__ Wch)
{
  const int bid = blockIdx.x;
  const float* src = (bid < 4096) ? x : (bid < 5120) ? Wk : (bid < 6144) ? Wv : Wc;
  unsigned short* dst = (bid < 4096) ? Xhi : (bid < 5120) ? Wkh
                        : (bid < 6144) ? Wvh : Wch;
  int i = (bid < 4096) ? bid * 256 + threadIdx.x
                       : ((bid - 4096) & 1023) * 256 + threadIdx.x;
  float4 v = reinterpret_cast<const float4*>(src)[i];
  ushort4 h;
  h.x = f2bf(v.x); h.y = f2bf(v.y); h.z = f2bf(v.z); h.w = f2bf(v.w);
  reinterpret_cast<ushort4*>(dst)[i] = h;
}

// Fused k/v projection GEMM, m97-structure: 128x128 tile, BK=64, plain bf16,
// global_load_lds w=16 into linear LDS with (row&7) XOR chunk swizzle.
// n-blocks 0..7 -> k = x@Wk^T ; 8..15 -> v = x@Wv^T. C emitted as bf16.
__global__ __launch_bounds__(256)
void gemm_kv(const unsigned short* __restrict__ Ah,
             const unsigned short* __restrict__ Wkh, const unsigned short* __restrict__ Wvh,
             unsigned short* __restrict__ Ck, unsigned short* __restrict__ Cv)
{
  __shared__ __attribute__((aligned(16))) unsigned short sAh[128 * 64];
  __shared__ __attribute__((aligned(16))) unsigned short sBh[128 * 64];
  const int bid = blockIdx.x;
  const int wg = (bid & 7) * 64 + (bid >> 3);   // XCD-bijective (512 = 8*64)
  const int bn = wg & 15, bm = wg >> 4;
  const bool kmode = (bn < 8);
  const unsigned short* __restrict__ Bsrc = kmode ? Wkh : Wvh;
  const int n0 = (kmode ? bn : bn - 8) * 128;
  const int m0 = bm * 128;
  const int tid = threadIdx.x;
  const int w = tid >> 6, lane = tid & 63;
  const int lrow = lane & 15, lg = lane >> 4;
  const int wr = w >> 1, wc = w & 1;            // 2x2 waves, 64x64 each
  const int srow = w * 8 + (lane >> 3);
  const int gsh = ((lane & 7) ^ (lane >> 3)) << 3;

  f32x4 acc[4][4];
#pragma unroll
  for (int i = 0; i < 4; ++i)
#pragma unroll
    for (int j = 0; j < 4; ++j) acc[i][j] = f32x4{0.f, 0.f, 0.f, 0.f};

  for (int k0 = 0; k0 < kC; k0 += 64) {
#pragma unroll
    for (int p = 0; p < 4; ++p) {
      const int r = p * 32 + srow;
      const int lb = (p * 32 + w * 8) * 64;
      gload16(&Ah[(size_t)(m0 + r) * kC + k0 + gsh], &sAh[lb]);
      gload16(&Bsrc[(size_t)(n0 + r) * kC + k0 + gsh], &sBh[lb]);
    }
    __syncthreads();   // implicit vmcnt(0) drain lands the glds data
#pragma unroll
    for (int ksl = 0; ksl < 2; ++ksl) {
      bf16x8 av[4], bv[4];
#pragma unroll
      for (int i = 0; i < 4; ++i)
        av[i] = ldsfrag(sAh, wr * 64 + i * 16 + lrow, ksl * 4 + lg);
#pragma unroll
      for (int j = 0; j < 4; ++j)
        bv[j] = ldsfrag(sBh, wc * 64 + j * 16 + lrow, ksl * 4 + lg);
#pragma unroll
      for (int i = 0; i < 4; ++i)
#pragma unroll
        for (int j = 0; j < 4; ++j)
          acc[i][j] = mfma16(av[i], bv[j], acc[i][j]);
    }
    __syncthreads();
  }

  unsigned short* __restrict__ C = kmode ? Ck : Cv;
#pragma unroll
  for (int i = 0; i < 4; ++i)
#pragma unroll
    for (int j = 0; j < 4; ++j)
#pragma unroll
      for (int r = 0; r < 4; ++r) {
        int row = m0 + wr * 64 + i * 16 + lg * 4 + r;
        int col = n0 + wc * 64 + j * 16 + lrow;
        C[(size_t)row * kC + col] = f2bf(acc[i][j][r]);
      }
}

// Output GEMM: out = y @ Wc^T, plain bf16, 128x64 tile.
__global__ __launch_bounds__(256)
void gemm_out(const unsigned short* __restrict__ Yh, const unsigned short* __restrict__ Wch,
              float* __restrict__ C)
{
  __shared__ __attribute__((aligned(16))) unsigned short sAh[128 * 64];
  __shared__ __attribute__((aligned(16))) unsigned short sBh[64 * 64];
  const int bid = blockIdx.x;
  const int wg = (bid & 7) * 64 + (bid >> 3);
  const int bn = wg & 15, bm = wg >> 4;
  const int n0 = bn * 64, m0 = bm * 128;
  const int tid = threadIdx.x;
  const int w = tid >> 6, lane = tid & 63;
  const int lrow = lane & 15, lg = lane >> 4;
  const int wr = w >> 1, wc = w & 1;
  const int srow = w * 8 + (lane >> 3);
  const int gsh = ((lane & 7) ^ (lane >> 3)) << 3;

  f32x4 acc[4][2];
#pragma unroll
  for (int i = 0; i < 4; ++i)
#pragma unroll
    for (int j = 0; j < 2; ++j) acc[i][j] = f32x4{0.f, 0.f, 0.f, 0.f};

  for (int k0 = 0; k0 < kC; k0 += 64) {
#pragma unroll
    for (int p = 0; p < 4; ++p) {
      const int r = p * 32 + srow;
      const int lb = (p * 32 + w * 8) * 64;
      gload16(&Yh[(size_t)(m0 + r) * kC + k0 + gsh], &sAh[lb]);
      if (p < 2) gload16(&Wch[(size_t)(n0 + r) * kC + k0 + gsh], &sBh[lb]);
    }
    __syncthreads();
#pragma unroll
    for (int ksl = 0; ksl < 2; ++ksl) {
      bf16x8 av[4], bv[2];
#pragma unroll
      for (int i = 0; i < 4; ++i)
        av[i] = ldsfrag(sAh, wr * 64 + i * 16 + lrow, ksl * 4 + lg);
#pragma unroll
      for (int j = 0; j < 2; ++j)
        bv[j] = ldsfrag(sBh, wc * 32 + j * 16 + lrow, ksl * 4 + lg);
#pragma unroll
      for (int i = 0; i < 4; ++i)
#pragma unroll
        for (int j = 0; j < 2; ++j)
          acc[i][j] = mfma16(av[i], bv[j], acc[i][j]);
    }
    __syncthreads();
  }
#pragma unroll
  for (int i = 0; i < 4; ++i)
#pragma unroll
    for (int j = 0; j < 2; ++j)
#pragma unroll
      for (int r = 0; r < 4; ++r) {
        int row = m0 + wr * 64 + i * 16 + lg * 4 + r;
        int col = n0 + wc * 32 + j * 16 + lrow;
        C[(size_t)row * kC + col] = acc[i][j][r];
      }
}

// Merged post-projection pass (one dispatch, 1536 blocks x 256):
//   blocks [0,1024)    : v blend + normalize + scale -> TRANSPOSED bf16 [b,h,d,t]
//   blocks [1024,1536) : fused decay scan (4 chunk-units per block, 1/wave)
// Inputs are bf16 (kraw16/vraw16). k scale carries sqrt(log2 e).
__global__ __launch_bounds__(256)
void post_kv(const unsigned short* __restrict__ vraw16, unsigned short* __restrict__ vtbf,
             const float* __restrict__ vcf, const float* __restrict__ vsc,
             const unsigned short* __restrict__ kraw16, const float* __restrict__ lkb,
             const float* __restrict__ ksc, unsigned short* __restrict__ kbf)
{
  const int bid = blockIdx.x;
  if (bid < 1024) {
    // ---- v blend + norm + transpose ----
    __shared__ __attribute__((aligned(16))) unsigned short Ts[64][72];
    const int nt = kT / 64;              // 32
    const int t0 = (bid % nt) * 64;
    const int h = (bid / nt) % kNH;
    const int b = bid / (nt * kNH);
    const int w = threadIdx.x >> 6, lane = threadIdx.x & 63;   // lane = d
    const float vc = vcf[h];
    const float sc = __expf(kES * vsc[h]);
    size_t idx = rowoff(b, t0 + w * 16) + h * kHS + lane;
    float cur = bf2f(vraw16[idx]);
#pragma unroll
    for (int i = 0; i < 16; ++i) {
      int t = t0 + w * 16 + i;
      float nxt = (t + 1 < kT) ? bf2f(vraw16[idx + kC]) : 0.f;
      float v = (1.f - vc) * nxt + vc * cur;
      float sq = v * v;
#pragma unroll
      for (int o = 1; o < 64; o <<= 1) sq += __shfl_xor(sq, o, 64);
      Ts[w * 16 + i][lane] = f2bf(v / (sqrtf(sq) + 1e-10f) * sc);
      cur = nxt;
      idx += kC;
    }
    __syncthreads();
    const int d = threadIdx.x >> 2, tc = (threadIdx.x & 3) * 16;
    us8 o0, o1;
#pragma unroll
    for (int i = 0; i < 8; ++i) o0[i] = Ts[tc + i][d];
#pragma unroll
    for (int i = 0; i < 8; ++i) o1[i] = Ts[tc + 8 + i][d];
    size_t vo = ((size_t)(b * kNH + h) * kHS + d) * kT + t0 + tc;
    *(us8*)&vtbf[vo] = o0;
    *(us8*)&vtbf[vo + 8] = o1;
  } else {
    // ---- fused decay scan + norm ----
    const int w = threadIdx.x >> 6;
    const int d = threadIdx.x & 63;
    const int unit = (bid - 1024) * 4 + w;         // 0..2047
    const int ch = unit % kNChunk;
    const int h = (unit / kNChunk) % kNH;
    const int b = unit / (kNChunk * kNH);
    const float lam = __expf(-fabsf(lkb[h]) * kES);
    const float kscale = __expf(fminf(kES * ksc[h], kKSM)) * kSqrtLog2e;

    float cprev = 0.f;
    if (ch > 0) {   // wave-uniform branch: scan previous chunk for the carry
      float s = 0.f;
      size_t idx = rowoff(b, (ch - 1) * kChunk) + h * kHS + d;
      for (int j = 0; j < kChunk; ++j) {
        s = bf2f(kraw16[idx]) + lam * s;
        idx += kC;
      }
      cprev = s;
    }

    float s = 0.f, lpow = 1.f;
    size_t idx = rowoff(b, ch * kChunk) + h * kHS + d;
    size_t ko = ((size_t)(b * kNH + h) * kT + ch * kChunk) * kHS + d;
    for (int j = 0; j < kChunk; ++j) {
      s = bf2f(kraw16[idx]) + lam * s;   // local prefix
      lpow *= lam;
      float v = s + lpow * cprev;
      float sq = v * v;
#pragma unroll
      for (int o = 1; o < 64; o <<= 1) sq += __shfl_xor(sq, o, 64);
      kbf[ko] = f2bf(v / (sqrtf(sq) + 1e-10f) * kscale);
      idx += kC;
      ko += kHS;
    }
  }
}

// MFMA flash attention: swapped-QK^T + fixed-shift softmax + XCD-local LPT;
// K staged sigma-permuted in LDS (each lane's 16 exp'd scores ARE its PV
// A-fragment); p = 2^s via hardware exp2; P packed via v_cvt_pk_bf16_f32.
// NEW: V is NOT staged in LDS — the PV B-fragment address is wave-invariant,
// so all 4 lockstep waves read the same 8KB V tile direct from global and
// the L1 serves waves 2-4 (v0+v1 jointly cover full 128B lines). V loads for
// tile t+1 issue right after tile t's PV consumes the registers (a full
// QK+exp+barrier ~400cyc covers latency). LDS pipe traffic halves; LDS
// footprint 36.9 -> 18.4 KB. sigma: [k5 k2 k4 k3 k1 k0].
__global__ __launch_bounds__(256)
void attn_mfma(const unsigned short* __restrict__ kbf,
               const unsigned short* __restrict__ vtbf,
               unsigned short* __restrict__ Yhi)
{
  constexpr int LD = 72;
  __shared__ __attribute__((aligned(16))) unsigned short Ks[2][64 * LD];
  const int f = blockIdx.x;            // 0..1023
  const int xcd = f & 7;
  const int g = f >> 3;
  const int bh = xcd * 4 + (g & 3);    // 4 (b,h) per XCD -> K/V L2-resident
  const int qt = 31 - (g >> 2);        // LPT: biggest q-tiles first
  const int b = bh >> 4, h = bh & 15;
  const int tid = threadIdx.x;
  const int w = tid >> 6, lane = tid & 63;
  const int lrow = lane & 15, lg = lane >> 4, lk = lg * 8;
  const size_t kbase = (size_t)bh * kT * kHS;   // [t][d]
  const size_t vbase = (size_t)bh * kHS * kT;   // [d][t]
  const int srow = tid >> 2, scs = (tid & 3) * 16;
  // sigma(srow): which LDS row physical key `srow` lands in
  const int sig = (srow & 32) | ((srow & 4) << 2) | ((srow & 24) >> 1) | (srow & 3);
  const int P0 = qt * 64;

  bf16x8 qf0, qf1;
  {
    size_t qoff = kbase + (size_t)(P0 + w * 16 + lrow) * kHS + lk;
    qf0 = *(const bf16x8*)&kbf[qoff];
    qf1 = *(const bf16x8*)&kbf[qoff + 32];
  }

  // per-lane V base pointers (direct global; wave-invariant -> L1-shared)
  const unsigned short* vp[4];
#pragma unroll
  for (int dt = 0; dt < 4; ++dt)
    vp[dt] = vtbf + vbase + (size_t)(dt * 16 + lrow) * kT + lk;

  f32x4 yac[4];
#pragma unroll
  for (int dt = 0; dt < 4; ++dt) yac[dt] = f32x4{0.f, 0.f, 0.f, 0.f};
  float lacc = 0.f;

  // prologue: issue V loads for tile 0; stage K tile 0 into Ks[0]
  bf16x8 vf0[4], vf1[4];
#pragma unroll
  for (int dt = 0; dt < 4; ++dt) {
    vf0[dt] = *(const bf16x8*)(vp[dt]);
    vf1[dt] = *(const bf16x8*)(vp[dt] + 32);
  }
  us8 nk0, nk1;
  {
    size_t gk = kbase + (size_t)srow * kHS + scs;
    nk0 = *(const us8*)&kbf[gk];
    nk1 = *(const us8*)&kbf[gk + 8];
  }
  *(us8*)&Ks[0][sig * LD + scs] = nk0;
  *(us8*)&Ks[0][sig * LD + scs + 8] = nk1;
  __syncthreads();

  int cur = 0;
  for (int j0 = 0; j0 <= P0; j0 += 64) {
    const bool more = (j0 + 64 <= P0);
    if (more) {   // issue next K-tile loads early (hidden under this tile)
      size_t gk = kbase + (size_t)(j0 + 64 + srow) * kHS + scs;
      nk0 = *(const us8*)&kbf[gk];
      nk1 = *(const us8*)&kbf[gk + 8];
    }

    // S^T = K Q^T (K rows sigma-permuted), acc pre-loaded with -7.5*log2e.
    // Lane (lg,lrow): s[kt][r] = log2e*(score - 7.5) for
    // key = (kt>>1)*32 + 8lg + (kt&1)*4 + r, query = lrow.
    f32x4 s[4];
    __builtin_amdgcn_s_setprio(1);
#pragma unroll
    for (int kt = 0; kt < 4; ++kt) {
      bf16x8 a0 = *(const bf16x8*)&Ks[cur][(kt * 16 + lrow) * LD + lk];
      bf16x8 a1 = *(const bf16x8*)&Ks[cur][(kt * 16 + lrow) * LD + lk + 32];
      f32x4 z = f32x4{kC4, kC4, kC4, kC4};
      z = mfma16(a0, qf0, z);
      z = mfma16(a1, qf1, z);
      s[kt] = z;
    }
    __builtin_amdgcn_s_setprio(0);

    // softmax numerator p = 2^s (hardware exp2); mask only on diagonal tile
    const int qg = P0 + w * 16 + lrow;   // this lane's query row
    float p[4][4];
    float psum = 0.f;
#pragma unroll
    for (int kt = 0; kt < 4; ++kt)
#pragma unroll
      for (int r = 0; r < 4; ++r) {
        float pv = __builtin_amdgcn_exp2f(s[kt][r]);
        if (j0 == P0) {
          int kg = j0 + (kt >> 1) * 32 + 8 * lg + ((kt & 1) << 2) + r;
          if (kg >= qg) pv = 0.f;
        }
        psum += pv;
        p[kt][r] = pv;
      }
    lacc += psum;

    // PA fragments built fully in-register (keys lg*8+j in slot order)
    union { int i[4]; bf16x8 v; } pa0u, pa1u;
    pa0u.i[0] = cvtpk(p[0][0], p[0][1]);
    pa0u.i[1] = cvtpk(p[0][2], p[0][3]);
    pa0u.i[2] = cvtpk(p[1][0], p[1][1]);
    pa0u.i[3] = cvtpk(p[1][2], p[1][3]);
    pa1u.i[0] = cvtpk(p[2][0], p[2][1]);
    pa1u.i[1] = cvtpk(p[2][2], p[2][3]);
    pa1u.i[2] = cvtpk(p[3][0], p[3][1]);
    pa1u.i[3] = cvtpk(p[3][2], p[3][3]);

    // PV: B-operands are the direct-loaded V fragments (tile j0)
    __builtin_amdgcn_s_setprio(1);
#pragma unroll
    for (int dt = 0; dt < 4; ++dt) {
      yac[dt] = mfma16(pa0u.v, vf0[dt], yac[dt]);
      yac[dt] = mfma16(pa1u.v, vf1[dt], yac[dt]);
    }
    __builtin_amdgcn_s_setprio(0);

    if (more) {
      *(us8*)&Ks[cur ^ 1][sig * LD + scs] = nk0;
      *(us8*)&Ks[cur ^ 1][sig * LD + scs + 8] = nk1;
      // issue V loads for tile j0+64 (land during next QK/exp)
#pragma unroll
      for (int dt = 0; dt < 4; ++dt) {
        vf0[dt] = *(const bf16x8*)(vp[dt] + j0 + 64);
        vf1[dt] = *(const bf16x8*)(vp[dt] + j0 + 64 + 32);
      }
    }
    __syncthreads();
    cur ^= 1;
  }

  lacc += __shfl_xor(lacc, 16, 64);
  lacc += __shfl_xor(lacc, 32, 64);
#pragma unroll
  for (int r = 0; r < 4; ++r) {
    float lq = __shfl(lacc, (lane & 48) | (lg * 4 + r), 64);
    int qg = P0 + w * 16 + lg * 4 + r;
    float inv = (qg >= 1) ? 1.f / lq : 0.f;
    size_t o = ((size_t)b * kT + qg) * kC + h * kHS;
#pragma unroll
    for (int dt = 0; dt < 4; ++dt)
      Yhi[o + dt * 16 + lrow] = f2bf(yac[dt][r] * inv);
  }
}

}  // namespace

extern "C" void kernel_launch(void* const* d_in, const int* in_sizes, int n_in,
                              void* d_out, int out_size, void* d_ws, size_t ws_size,
                              hipStream_t stream)
{
  const float* x   = (const float*)d_in[0];
  const float* Wk  = (const float*)d_in[1];
  const float* Wv  = (const float*)d_in[2];
  const float* Wc  = (const float*)d_in[3];
  const float* lkb = (const float*)d_in[4];
  const float* ksc = (const float*)d_in[5];
  const float* vcf = (const float*)d_in[6];
  const float* vsc = (const float*)d_in[7];
  float* out = (float*)d_out;

  // Workspace map (time-multiplexed):
  float* wsf = (float*)d_ws;
  unsigned short* vraw16 = (unsigned short*)wsf;   // 4,194,304 shorts — raw v bf16
  unsigned short* shA = (unsigned short*)(wsf + 4325376);  // 8,388,608 shorts region
  unsigned short* Xhi = shA;                       // phase 1: x bf16
  unsigned short* kbf  = shA;                      // phase 2: bf16 k [b,h,t,d]
  unsigned short* vtbf = shA + 4194304;            //          bf16 v^T [b,h,d,t]
  unsigned short* Wkh = (unsigned short*)(wsf + 8519680); // 3 x 1,048,576 shorts
  unsigned short* Wvh = Wkh + 1048576;
  unsigned short* Wch = Wvh + 1048576;
  unsigned short* Yhi = (unsigned short*)wsf;      // phase 3: y bf16 (vraw16 dead)
  unsigned short* kraw16 = (unsigned short*)out;   // d_out hosts bf16 k_raw
                                                   // until final GEMM overwrites

  // all splits in one dispatch (all plain bf16)
  split_all<<<7168, 256, 0, stream>>>(x, Xhi, Wk, Wkh, Wv, Wvh, Wc, Wch);

  // fused k + v projection GEMM (bf16 in, bf16 out)
  gemm_kv<<<512, 256, 0, stream>>>(Xhi, Wkh, Wvh, kraw16, vraw16);

  // merged decay scan + v blend/norm/transpose (kbf overwrites Xhi)
  post_kv<<<1536, 256, 0, stream>>>(vraw16, vtbf, vcf, vsc, kraw16, lkb, ksc, kbf);

  // flash attention: reads kbf/vtbf, writes Yhi (vraw16 region, now dead)
  attn_mfma<<<1024, 256, 0, stream>>>(kbf, vtbf, Yhi);

  // out = y @ Wc^T  (plain bf16)
  gemm_out<<<512, 256, 0, stream>>>(Yhi, Wch, out);
}

// Round 18
// 109.979 us; speedup vs baseline: 1.3584x; 1.3584x over previous
//
#include <hip/hip_runtime.h>
#include <hip/hip_bf16.h>
#include <math.h>

namespace {

constexpr int kB = 2, kT = 2048, kC = 1024, kNH = 16, kHS = 64;
constexpr int kM = kB * kT;                 // 4096 rows
constexpr int kChunk = 32, kNChunk = kT / kChunk;   // decay scan chunking
constexpr float kES = 10.0f;                // EXP_SCALING
constexpr float kKSM = 11.090339630053647f; // log(2^16 - 1)
// |q.k| <= |q||k| = e^2 = 7.389 (k rows unit-L2 scaled by exp(1)).
// kbf additionally carries sqrt(log2 e) on both q and k, so MFMA scores are
// log2e*(q.k); with C-init = -7.5*log2e, p = exp2(s) = exp(q.k - 7.5) exactly.
constexpr float kSqrtLog2e = 1.2011224087864498f;
constexpr float kC4 = -10.820212806667226f;  // -7.5 * log2(e)

typedef __attribute__((ext_vector_type(8))) short bf16x8;
typedef __attribute__((ext_vector_type(4))) float f32x4;
typedef __attribute__((ext_vector_type(8))) unsigned short us8;

__device__ __forceinline__ size_t rowoff(int b, int t) {
  return ((size_t)b * kT + t) * kC;
}

// fp32 -> bf16 bits, round-to-nearest-even
__device__ __forceinline__ unsigned short f2bf(float f) {
  unsigned int u = __float_as_uint(f);
  u += 0x7fffu + ((u >> 16) & 1u);
  return (unsigned short)(u >> 16);
}
__device__ __forceinline__ float bf2f(unsigned short h) {
  return __uint_as_float((unsigned int)h << 16);
}

__device__ __forceinline__ f32x4 mfma16(bf16x8 a, bf16x8 b, f32x4 c) {
  return __builtin_amdgcn_mfma_f32_16x16x32_bf16(a, b, c, 0, 0, 0);
}

// pack two f32 -> dword of 2 bf16 (lo = a, hi = b)
__device__ __forceinline__ int cvtpk(float a, float b) {
  int r;
  asm("v_cvt_pk_bf16_f32 %0, %1, %2" : "=v"(r) : "v"(a), "v"(b));
  return r;
}

// async global->LDS, 16B per lane. LDS dest = wave-uniform base + lane*16.
__device__ __forceinline__ void gload16(const unsigned short* g, unsigned short* l) {
  __builtin_amdgcn_global_load_lds(
      (const __attribute__((address_space(1))) unsigned int*)g,
      (__attribute__((address_space(3))) unsigned int*)l, 16, 0, 0);
}

// swizzled fragment read: 8 shorts of (row, 16B-chunk cg) in a [*][64]-short
// linear tile where chunk slots are XOR'd by (row&7).
__device__ __forceinline__ bf16x8 ldsfrag(const unsigned short* arr, int row, int cg) {
  return *(const bf16x8*)&arr[row * 64 + ((cg ^ (row & 7)) << 3)];
}

// All input splits in one dispatch (all plain bf16):
//   blocks [0,4096)      : x -> Xhi
//   blocks [4096,5120)   : Wk -> Wkh
//   blocks [5120,6144)   : Wv -> Wvh
//   blocks [6144,7168)   : Wc -> Wch
__global__ __launch_bounds__(256)
void split_all(const float* __restrict__ x, unsigned short* __restrict__ Xhi,
               const float* __restrict__ Wk, unsigned short* __restrict__ Wkh,
               const float* __restrict__ Wv, unsigned short* __restrict__ Wvh,
               const float* __restrict__ Wc, unsigned short* __restrict__ Wch)
{
  const int bid = blockIdx.x;
  const float* src = (bid < 4096) ? x : (bid < 5120) ? Wk : (bid < 6144) ? Wv : Wc;
  unsigned short* dst = (bid < 4096) ? Xhi : (bid < 5120) ? Wkh
                        : (bid < 6144) ? Wvh : Wch;
  int i = (bid < 4096) ? bid * 256 + threadIdx.x
                       : ((bid - 4096) & 1023) * 256 + threadIdx.x;
  float4 v = reinterpret_cast<const float4*>(src)[i];
  ushort4 h;
  h.x = f2bf(v.x); h.y = f2bf(v.y); h.z = f2bf(v.z); h.w = f2bf(v.w);
  reinterpret_cast<ushort4*>(dst)[i] = h;
}

// Fused k/v projection GEMM, m97-structure: 128x128 tile, BK=64, plain bf16,
// global_load_lds w=16 into linear LDS with (row&7) XOR chunk swizzle.
// n-blocks 0..7 -> k = x@Wk^T ; 8..15 -> v = x@Wv^T. C emitted as bf16.
__global__ __launch_bounds__(256)
void gemm_kv(const unsigned short* __restrict__ Ah,
             const unsigned short* __restrict__ Wkh, const unsigned short* __restrict__ Wvh,
             unsigned short* __restrict__ Ck, unsigned short* __restrict__ Cv)
{
  __shared__ __attribute__((aligned(16))) unsigned short sAh[128 * 64];
  __shared__ __attribute__((aligned(16))) unsigned short sBh[128 * 64];
  const int bid = blockIdx.x;
  const int wg = (bid & 7) * 64 + (bid >> 3);   // XCD-bijective (512 = 8*64)
  const int bn = wg & 15, bm = wg >> 4;
  const bool kmode = (bn < 8);
  const unsigned short* __restrict__ Bsrc = kmode ? Wkh : Wvh;
  const int n0 = (kmode ? bn : bn - 8) * 128;
  const int m0 = bm * 128;
  const int tid = threadIdx.x;
  const int w = tid >> 6, lane = tid & 63;
  const int lrow = lane & 15, lg = lane >> 4;
  const int wr = w >> 1, wc = w & 1;            // 2x2 waves, 64x64 each
  const int srow = w * 8 + (lane >> 3);
  const int gsh = ((lane & 7) ^ (lane >> 3)) << 3;

  f32x4 acc[4][4];
#pragma unroll
  for (int i = 0; i < 4; ++i)
#pragma unroll
    for (int j = 0; j < 4; ++j) acc[i][j] = f32x4{0.f, 0.f, 0.f, 0.f};

  for (int k0 = 0; k0 < kC; k0 += 64) {
#pragma unroll
    for (int p = 0; p < 4; ++p) {
      const int r = p * 32 + srow;
      const int lb = (p * 32 + w * 8) * 64;
      gload16(&Ah[(size_t)(m0 + r) * kC + k0 + gsh], &sAh[lb]);
      gload16(&Bsrc[(size_t)(n0 + r) * kC + k0 + gsh], &sBh[lb]);
    }
    __syncthreads();   // implicit vmcnt(0) drain lands the glds data
#pragma unroll
    for (int ksl = 0; ksl < 2; ++ksl) {
      bf16x8 av[4], bv[4];
#pragma unroll
      for (int i = 0; i < 4; ++i)
        av[i] = ldsfrag(sAh, wr * 64 + i * 16 + lrow, ksl * 4 + lg);
#pragma unroll
      for (int j = 0; j < 4; ++j)
        bv[j] = ldsfrag(sBh, wc * 64 + j * 16 + lrow, ksl * 4 + lg);
#pragma unroll
      for (int i = 0; i < 4; ++i)
#pragma unroll
        for (int j = 0; j < 4; ++j)
          acc[i][j] = mfma16(av[i], bv[j], acc[i][j]);
    }
    __syncthreads();
  }

  unsigned short* __restrict__ C = kmode ? Ck : Cv;
#pragma unroll
  for (int i = 0; i < 4; ++i)
#pragma unroll
    for (int j = 0; j < 4; ++j)
#pragma unroll
      for (int r = 0; r < 4; ++r) {
        int row = m0 + wr * 64 + i * 16 + lg * 4 + r;
        int col = n0 + wc * 64 + j * 16 + lrow;
        C[(size_t)row * kC + col] = f2bf(acc[i][j][r]);
      }
}

// Output GEMM: out = y @ Wc^T, plain bf16, 128x64 tile.
__global__ __launch_bounds__(256)
void gemm_out(const unsigned short* __restrict__ Yh, const unsigned short* __restrict__ Wch,
              float* __restrict__ C)
{
  __shared__ __attribute__((aligned(16))) unsigned short sAh[128 * 64];
  __shared__ __attribute__((aligned(16))) unsigned short sBh[64 * 64];
  const int bid = blockIdx.x;
  const int wg = (bid & 7) * 64 + (bid >> 3);
  const int bn = wg & 15, bm = wg >> 4;
  const int n0 = bn * 64, m0 = bm * 128;
  const int tid = threadIdx.x;
  const int w = tid >> 6, lane = tid & 63;
  const int lrow = lane & 15, lg = lane >> 4;
  const int wr = w >> 1, wc = w & 1;
  const int srow = w * 8 + (lane >> 3);
  const int gsh = ((lane & 7) ^ (lane >> 3)) << 3;

  f32x4 acc[4][2];
#pragma unroll
  for (int i = 0; i < 4; ++i)
#pragma unroll
    for (int j = 0; j < 2; ++j) acc[i][j] = f32x4{0.f, 0.f, 0.f, 0.f};

  for (int k0 = 0; k0 < kC; k0 += 64) {
#pragma unroll
    for (int p = 0; p < 4; ++p) {
      const int r = p * 32 + srow;
      const int lb = (p * 32 + w * 8) * 64;
      gload16(&Yh[(size_t)(m0 + r) * kC + k0 + gsh], &sAh[lb]);
      if (p < 2) gload16(&Wch[(size_t)(n0 + r) * kC + k0 + gsh], &sBh[lb]);
    }
    __syncthreads();
#pragma unroll
    for (int ksl = 0; ksl < 2; ++ksl) {
      bf16x8 av[4], bv[2];
#pragma unroll
      for (int i = 0; i < 4; ++i)
        av[i] = ldsfrag(sAh, wr * 64 + i * 16 + lrow, ksl * 4 + lg);
#pragma unroll
      for (int j = 0; j < 2; ++j)
        bv[j] = ldsfrag(sBh, wc * 32 + j * 16 + lrow, ksl * 4 + lg);
#pragma unroll
      for (int i = 0; i < 4; ++i)
#pragma unroll
        for (int j = 0; j < 2; ++j)
          acc[i][j] = mfma16(av[i], bv[j], acc[i][j]);
    }
    __syncthreads();
  }
#pragma unroll
  for (int i = 0; i < 4; ++i)
#pragma unroll
    for (int j = 0; j < 2; ++j)
#pragma unroll
      for (int r = 0; r < 4; ++r) {
        int row = m0 + wr * 64 + i * 16 + lg * 4 + r;
        int col = n0 + wc * 32 + j * 16 + lrow;
        C[(size_t)row * kC + col] = acc[i][j][r];
      }
}

// Merged post-projection pass (one dispatch, 1536 blocks x 256):
//   blocks [0,1024)    : v blend + normalize + scale -> TRANSPOSED bf16 [b,h,d,t]
//   blocks [1024,1536) : fused decay scan (4 chunk-units per block, 1/wave)
// Inputs are bf16 (kraw16/vraw16). k scale carries sqrt(log2 e).
__global__ __launch_bounds__(256)
void post_kv(const unsigned short* __restrict__ vraw16, unsigned short* __restrict__ vtbf,
             const float* __restrict__ vcf, const float* __restrict__ vsc,
             const unsigned short* __restrict__ kraw16, const float* __restrict__ lkb,
             const float* __restrict__ ksc, unsigned short* __restrict__ kbf)
{
  const int bid = blockIdx.x;
  if (bid < 1024) {
    // ---- v blend + norm + transpose ----
    __shared__ __attribute__((aligned(16))) unsigned short Ts[64][72];
    const int nt = kT / 64;              // 32
    const int t0 = (bid % nt) * 64;
    const int h = (bid / nt) % kNH;
    const int b = bid / (nt * kNH);
    const int w = threadIdx.x >> 6, lane = threadIdx.x & 63;   // lane = d
    const float vc = vcf[h];
    const float sc = __expf(kES * vsc[h]);
    size_t idx = rowoff(b, t0 + w * 16) + h * kHS + lane;
    float cur = bf2f(vraw16[idx]);
#pragma unroll
    for (int i = 0; i < 16; ++i) {
      int t = t0 + w * 16 + i;
      float nxt = (t + 1 < kT) ? bf2f(vraw16[idx + kC]) : 0.f;
      float v = (1.f - vc) * nxt + vc * cur;
      float sq = v * v;
#pragma unroll
      for (int o = 1; o < 64; o <<= 1) sq += __shfl_xor(sq, o, 64);
      Ts[w * 16 + i][lane] = f2bf(v / (sqrtf(sq) + 1e-10f) * sc);
      cur = nxt;
      idx += kC;
    }
    __syncthreads();
    const int d = threadIdx.x >> 2, tc = (threadIdx.x & 3) * 16;
    us8 o0, o1;
#pragma unroll
    for (int i = 0; i < 8; ++i) o0[i] = Ts[tc + i][d];
#pragma unroll
    for (int i = 0; i < 8; ++i) o1[i] = Ts[tc + 8 + i][d];
    size_t vo = ((size_t)(b * kNH + h) * kHS + d) * kT + t0 + tc;
    *(us8*)&vtbf[vo] = o0;
    *(us8*)&vtbf[vo + 8] = o1;
  } else {
    // ---- fused decay scan + norm ----
    const int w = threadIdx.x >> 6;
    const int d = threadIdx.x & 63;
    const int unit = (bid - 1024) * 4 + w;         // 0..2047
    const int ch = unit % kNChunk;
    const int h = (unit / kNChunk) % kNH;
    const int b = unit / (kNChunk * kNH);
    const float lam = __expf(-fabsf(lkb[h]) * kES);
    const float kscale = __expf(fminf(kES * ksc[h], kKSM)) * kSqrtLog2e;

    float cprev = 0.f;
    if (ch > 0) {   // wave-uniform branch: scan previous chunk for the carry
      float s = 0.f;
      size_t idx = rowoff(b, (ch - 1) * kChunk) + h * kHS + d;
      for (int j = 0; j < kChunk; ++j) {
        s = bf2f(kraw16[idx]) + lam * s;
        idx += kC;
      }
      cprev = s;
    }

    float s = 0.f, lpow = 1.f;
    size_t idx = rowoff(b, ch * kChunk) + h * kHS + d;
    size_t ko = ((size_t)(b * kNH + h) * kT + ch * kChunk) * kHS + d;
    for (int j = 0; j < kChunk; ++j) {
      s = bf2f(kraw16[idx]) + lam * s;   // local prefix
      lpow *= lam;
      float v = s + lpow * cprev;
      float sq = v * v;
#pragma unroll
      for (int o = 1; o < 64; o <<= 1) sq += __shfl_xor(sq, o, 64);
      kbf[ko] = f2bf(v / (sqrtf(sq) + 1e-10f) * kscale);
      idx += kC;
      ko += kHS;
    }
  }
}

// MFMA flash attention (round-16 verbatim, proven 44.5 us): swapped-QK^T +
// fixed-shift softmax + XCD-local LPT; K AND V double-buffered in LDS;
// K staged sigma-permuted (each lane's 16 exp'd scores ARE its PV
// A-fragment); p = 2^s via hardware exp2; P packed via v_cvt_pk_bf16_f32.
// sigma: [k5 k2 k4 k3 k1 k0]. Three structural alternatives measured worse
// (R10 fewer-blocks 61us, R12 no-LDS 145us, R17 V-direct 84us) — this
// structure is final; floor = LDS pipe + barrier drain.
__global__ __launch_bounds__(256)
void attn_mfma(const unsigned short* __restrict__ kbf,
               const unsigned short* __restrict__ vtbf,
               unsigned short* __restrict__ Yhi)
{
  constexpr int LD = 72;
  __shared__ __attribute__((aligned(16))) unsigned short Ks[2][64 * LD];
  __shared__ __attribute__((aligned(16))) unsigned short Vs[2][64 * LD];
  const int f = blockIdx.x;            // 0..1023
  const int xcd = f & 7;
  const int g = f >> 3;
  const int bh = xcd * 4 + (g & 3);    // 4 (b,h) per XCD -> K/V L2-resident
  const int qt = 31 - (g >> 2);        // LPT: biggest q-tiles first
  const int b = bh >> 4, h = bh & 15;
  const int tid = threadIdx.x;
  const int w = tid >> 6, lane = tid & 63;
  const int lrow = lane & 15, lg = lane >> 4, lk = lg * 8;
  const size_t kbase = (size_t)bh * kT * kHS;   // [t][d]
  const size_t vbase = (size_t)bh * kHS * kT;   // [d][t]
  const int srow = tid >> 2, scs = (tid & 3) * 16;
  // sigma(srow): which LDS row physical key `srow` lands in
  const int sig = (srow & 32) | ((srow & 4) << 2) | ((srow & 24) >> 1) | (srow & 3);
  const int P0 = qt * 64;

  bf16x8 qf0, qf1;
  {
    size_t qoff = kbase + (size_t)(P0 + w * 16 + lrow) * kHS + lk;
    qf0 = *(const bf16x8*)&kbf[qoff];
    qf1 = *(const bf16x8*)&kbf[qoff + 32];
  }

  f32x4 yac[4];
#pragma unroll
  for (int dt = 0; dt < 4; ++dt) yac[dt] = f32x4{0.f, 0.f, 0.f, 0.f};
  float lacc = 0.f;

  us8 nk0, nk1, nv0, nv1;
  {
    size_t gk = kbase + (size_t)srow * kHS + scs;
    nk0 = *(const us8*)&kbf[gk];
    nk1 = *(const us8*)&kbf[gk + 8];
    size_t gv = vbase + (size_t)srow * kT + scs;
    nv0 = *(const us8*)&vtbf[gv];
    nv1 = *(const us8*)&vtbf[gv + 8];
  }
  *(us8*)&Ks[0][sig * LD + scs] = nk0;
  *(us8*)&Ks[0][sig * LD + scs + 8] = nk1;
  *(us8*)&Vs[0][srow * LD + scs] = nv0;
  *(us8*)&Vs[0][srow * LD + scs + 8] = nv1;
  __syncthreads();

  int cur = 0;
  for (int j0 = 0; j0 <= P0; j0 += 64) {
    const bool more = (j0 + 64 <= P0);
    if (more) {
      size_t gk = kbase + (size_t)(j0 + 64 + srow) * kHS + scs;
      nk0 = *(const us8*)&kbf[gk];
      nk1 = *(const us8*)&kbf[gk + 8];
      size_t gv = vbase + (size_t)srow * kT + j0 + 64 + scs;
      nv0 = *(const us8*)&vtbf[gv];
      nv1 = *(const us8*)&vtbf[gv + 8];
    }

    // S^T = K Q^T (K rows sigma-permuted), acc pre-loaded with -7.5*log2e.
    // Lane (lg,lrow): s[kt][r] = log2e*(score - 7.5) for
    // key = (kt>>1)*32 + 8lg + (kt&1)*4 + r, query = lrow.
    f32x4 s[4];
    __builtin_amdgcn_s_setprio(1);
#pragma unroll
    for (int kt = 0; kt < 4; ++kt) {
      bf16x8 a0 = *(const bf16x8*)&Ks[cur][(kt * 16 + lrow) * LD + lk];
      bf16x8 a1 = *(const bf16x8*)&Ks[cur][(kt * 16 + lrow) * LD + lk + 32];
      f32x4 z = f32x4{kC4, kC4, kC4, kC4};
      z = mfma16(a0, qf0, z);
      z = mfma16(a1, qf1, z);
      s[kt] = z;
    }
    __builtin_amdgcn_s_setprio(0);

    // softmax numerator p = 2^s (hardware exp2); mask only on diagonal tile
    const int qg = P0 + w * 16 + lrow;   // this lane's query row
    float p[4][4];
    float psum = 0.f;
#pragma unroll
    for (int kt = 0; kt < 4; ++kt)
#pragma unroll
      for (int r = 0; r < 4; ++r) {
        float pv = __builtin_amdgcn_exp2f(s[kt][r]);
        if (j0 == P0) {
          int kg = j0 + (kt >> 1) * 32 + 8 * lg + ((kt & 1) << 2) + r;
          if (kg >= qg) pv = 0.f;
        }
        psum += pv;
        p[kt][r] = pv;
      }
    lacc += psum;

    // PA fragments built fully in-register (keys lg*8+j in slot order)
    union { int i[4]; bf16x8 v; } pa0u, pa1u;
    pa0u.i[0] = cvtpk(p[0][0], p[0][1]);
    pa0u.i[1] = cvtpk(p[0][2], p[0][3]);
    pa0u.i[2] = cvtpk(p[1][0], p[1][1]);
    pa0u.i[3] = cvtpk(p[1][2], p[1][3]);
    pa1u.i[0] = cvtpk(p[2][0], p[2][1]);
    pa1u.i[1] = cvtpk(p[2][2], p[2][3]);
    pa1u.i[2] = cvtpk(p[3][0], p[3][1]);
    pa1u.i[3] = cvtpk(p[3][2], p[3][3]);

    __builtin_amdgcn_s_setprio(1);
#pragma unroll
    for (int dt = 0; dt < 4; ++dt) {
      bf16x8 v0 = *(const bf16x8*)&Vs[cur][(dt * 16 + lrow) * LD + lk];
      bf16x8 v1 = *(const bf16x8*)&Vs[cur][(dt * 16 + lrow) * LD + lk + 32];
      yac[dt] = mfma16(pa0u.v, v0, yac[dt]);
      yac[dt] = mfma16(pa1u.v, v1, yac[dt]);
    }
    __builtin_amdgcn_s_setprio(0);

    if (more) {
      *(us8*)&Ks[cur ^ 1][sig * LD + scs] = nk0;
      *(us8*)&Ks[cur ^ 1][sig * LD + scs + 8] = nk1;
      *(us8*)&Vs[cur ^ 1][srow * LD + scs] = nv0;
      *(us8*)&Vs[cur ^ 1][srow * LD + scs + 8] = nv1;
    }
    __syncthreads();
    cur ^= 1;
  }

  lacc += __shfl_xor(lacc, 16, 64);
  lacc += __shfl_xor(lacc, 32, 64);
#pragma unroll
  for (int r = 0; r < 4; ++r) {
    float lq = __shfl(lacc, (lane & 48) | (lg * 4 + r), 64);
    int qg = P0 + w * 16 + lg * 4 + r;
    float inv = (qg >= 1) ? 1.f / lq : 0.f;
    size_t o = ((size_t)b * kT + qg) * kC + h * kHS;
#pragma unroll
    for (int dt = 0; dt < 4; ++dt)
      Yhi[o + dt * 16 + lrow] = f2bf(yac[dt][r] * inv);
  }
}

}  // namespace

extern "C" void kernel_launch(void* const* d_in, const int* in_sizes, int n_in,
                              void* d_out, int out_size, void* d_ws, size_t ws_size,
                              hipStream_t stream)
{
  const float* x   = (const float*)d_in[0];
  const float* Wk  = (const float*)d_in[1];
  const float* Wv  = (const float*)d_in[2];
  const float* Wc  = (const float*)d_in[3];
  const float* lkb = (const float*)d_in[4];
  const float* ksc = (const float*)d_in[5];
  const float* vcf = (const float*)d_in[6];
  const float* vsc = (const float*)d_in[7];
  float* out = (float*)d_out;

  // Workspace map (time-multiplexed):
  float* wsf = (float*)d_ws;
  unsigned short* vraw16 = (unsigned short*)wsf;   // 4,194,304 shorts — raw v bf16
  unsigned short* shA = (unsigned short*)(wsf + 4325376);  // 8,388,608 shorts region
  unsigned short* Xhi = shA;                       // phase 1: x bf16
  unsigned short* kbf  = shA;                      // phase 2: bf16 k [b,h,t,d]
  unsigned short* vtbf = shA + 4194304;            //          bf16 v^T [b,h,d,t]
  unsigned short* Wkh = (unsigned short*)(wsf + 8519680); // 3 x 1,048,576 shorts
  unsigned short* Wvh = Wkh + 1048576;
  unsigned short* Wch = Wvh + 1048576;
  unsigned short* Yhi = (unsigned short*)wsf;      // phase 3: y bf16 (vraw16 dead)
  unsigned short* kraw16 = (unsigned short*)out;   // d_out hosts bf16 k_raw
                                                   // until final GEMM overwrites

  // all splits in one dispatch (all plain bf16)
  split_all<<<7168, 256, 0, stream>>>(x, Xhi, Wk, Wkh, Wv, Wvh, Wc, Wch);

  // fused k + v projection GEMM (bf16 in, bf16 out)
  gemm_kv<<<512, 256, 0, stream>>>(Xhi, Wkh, Wvh, kraw16, vraw16);

  // merged decay scan + v blend/norm/transpose (kbf overwrites Xhi)
  post_kv<<<1536, 256, 0, stream>>>(vraw16, vtbf, vcf, vsc, kraw16, lkb, ksc, kbf);

  // flash attention: reads kbf/vtbf, writes Yhi (vraw16 region, now dead)
  attn_mfma<<<1024, 256, 0, stream>>>(kbf, vtbf, Yhi);

  // out = y @ Wc^T  (plain bf16)
  gemm_out<<<512, 256, 0, stream>>>(Yhi, Wch, out);
}

// Round 19
// 107.154 us; speedup vs baseline: 1.3942x; 1.0264x over previous
//
#include <hip/hip_runtime.h>
#include <hip/hip_bf16.h>
#include <math.h>

namespace {

constexpr int kB = 2, kT = 2048, kC = 1024, kNH = 16, kHS = 64;
constexpr int kM = kB * kT;                 // 4096 rows
constexpr int kChunk = 32, kNChunk = kT / kChunk;   // decay scan chunking
constexpr float kES = 10.0f;                // EXP_SCALING
constexpr float kKSM = 11.090339630053647f; // log(2^16 - 1)
// |q.k| <= |q||k| = e^2 = 7.389 (k rows unit-L2 scaled by exp(1)).
// kbf additionally carries sqrt(log2 e) on both q and k, so MFMA scores are
// log2e*(q.k); with C-init = -7.5*log2e, p = exp2(s) = exp(q.k - 7.5) exactly.
constexpr float kSqrtLog2e = 1.2011224087864498f;
constexpr float kC4 = -10.820212806667226f;  // -7.5 * log2(e)

typedef __attribute__((ext_vector_type(8))) short bf16x8;
typedef __attribute__((ext_vector_type(4))) float f32x4;
typedef __attribute__((ext_vector_type(8))) unsigned short us8;

__device__ __forceinline__ size_t rowoff(int b, int t) {
  return ((size_t)b * kT + t) * kC;
}

// fp32 -> bf16 bits, round-to-nearest-even
__device__ __forceinline__ unsigned short f2bf(float f) {
  unsigned int u = __float_as_uint(f);
  u += 0x7fffu + ((u >> 16) & 1u);
  return (unsigned short)(u >> 16);
}
__device__ __forceinline__ float bf2f(unsigned short h) {
  return __uint_as_float((unsigned int)h << 16);
}

__device__ __forceinline__ f32x4 mfma16(bf16x8 a, bf16x8 b, f32x4 c) {
  return __builtin_amdgcn_mfma_f32_16x16x32_bf16(a, b, c, 0, 0, 0);
}

// pack two f32 -> dword of 2 bf16 (lo = a, hi = b)
__device__ __forceinline__ int cvtpk(float a, float b) {
  int r;
  asm("v_cvt_pk_bf16_f32 %0, %1, %2" : "=v"(r) : "v"(a), "v"(b));
  return r;
}

// async global->LDS, 16B per lane. LDS dest = wave-uniform base + lane*16.
__device__ __forceinline__ void gload16(const unsigned short* g, unsigned short* l) {
  __builtin_amdgcn_global_load_lds(
      (const __attribute__((address_space(1))) unsigned int*)g,
      (__attribute__((address_space(3))) unsigned int*)l, 16, 0, 0);
}

// swizzled fragment read, 128-short rows (BK=128): 8 shorts of (row, chunk cg)
// where chunk slots are XOR'd by (row&7). cg in [0,16).
__device__ __forceinline__ bf16x8 ldsfrag128(const unsigned short* arr, int row, int cg) {
  return *(const bf16x8*)&arr[row * 128 + ((cg ^ (row & 7)) << 3)];
}

// All input splits in one dispatch (all plain bf16):
//   blocks [0,4096)      : x -> Xhi
//   blocks [4096,5120)   : Wk -> Wkh
//   blocks [5120,6144)   : Wv -> Wvh
//   blocks [6144,7168)   : Wc -> Wch
__global__ __launch_bounds__(256)
void split_all(const float* __restrict__ x, unsigned short* __restrict__ Xhi,
               const float* __restrict__ Wk, unsigned short* __restrict__ Wkh,
               const float* __restrict__ Wv, unsigned short* __restrict__ Wvh,
               const float* __restrict__ Wc, unsigned short* __restrict__ Wch)
{
  const int bid = blockIdx.x;
  const float* src = (bid < 4096) ? x : (bid < 5120) ? Wk : (bid < 6144) ? Wv : Wc;
  unsigned short* dst = (bid < 4096) ? Xhi : (bid < 5120) ? Wkh
                        : (bid < 6144) ? Wvh : Wch;
  int i = (bid < 4096) ? bid * 256 + threadIdx.x
                       : ((bid - 4096) & 1023) * 256 + threadIdx.x;
  float4 v = reinterpret_cast<const float4*>(src)[i];
  ushort4 h;
  h.x = f2bf(v.x); h.y = f2bf(v.y); h.z = f2bf(v.z); h.w = f2bf(v.w);
  reinterpret_cast<ushort4*>(dst)[i] = h;
}

// Fused k/v projection GEMM: 128x128 tile, BK=128 (both GEMMs are
// grid-limited at 2 blocks/CU, so 64KB LDS costs no occupancy and halves
// the per-K-step barrier drains: 32 -> 16). global_load_lds w=16 into
// linear LDS, (row&7) XOR chunk swizzle on 16-chunk rows.
// n-blocks 0..7 -> k = x@Wk^T ; 8..15 -> v = x@Wv^T. C emitted as bf16.
__global__ __launch_bounds__(256)
void gemm_kv(const unsigned short* __restrict__ Ah,
             const unsigned short* __restrict__ Wkh, const unsigned short* __restrict__ Wvh,
             unsigned short* __restrict__ Ck, unsigned short* __restrict__ Cv)
{
  __shared__ __attribute__((aligned(16))) unsigned short sAh[128 * 128];
  __shared__ __attribute__((aligned(16))) unsigned short sBh[128 * 128];
  const int bid = blockIdx.x;
  const int wg = (bid & 7) * 64 + (bid >> 3);   // XCD-bijective (512 = 8*64)
  const int bn = wg & 15, bm = wg >> 4;
  const bool kmode = (bn < 8);
  const unsigned short* __restrict__ Bsrc = kmode ? Wkh : Wvh;
  const int n0 = (kmode ? bn : bn - 8) * 128;
  const int m0 = bm * 128;
  const int tid = threadIdx.x;
  const int w = tid >> 6, lane = tid & 63;
  const int lrow = lane & 15, lg = lane >> 4;
  const int wr = w >> 1, wc = w & 1;            // 2x2 waves, 64x64 each
  // staging (BK=128 rows of 16 chunks): wave covers 4 rows per pass
  const int sr4 = w * 4 + (lane >> 4);          // row within 16-row pass
  const int gsh = (((lane & 15) ^ (sr4 & 7)) << 3);  // pre-swizzled chunk

  f32x4 acc[4][4];
#pragma unroll
  for (int i = 0; i < 4; ++i)
#pragma unroll
    for (int j = 0; j < 4; ++j) acc[i][j] = f32x4{0.f, 0.f, 0.f, 0.f};

  for (int k0 = 0; k0 < kC; k0 += 128) {
#pragma unroll
    for (int p = 0; p < 8; ++p) {
      const int r = p * 16 + sr4;
      const int lb = (p * 16 + w * 4) * 128;    // wave-uniform LDS base
      gload16(&Ah[(size_t)(m0 + r) * kC + k0 + gsh], &sAh[lb]);
      gload16(&Bsrc[(size_t)(n0 + r) * kC + k0 + gsh], &sBh[lb]);
    }
    __syncthreads();   // implicit vmcnt(0) drain lands the glds data
#pragma unroll
    for (int ksl = 0; ksl < 4; ++ksl) {
      bf16x8 av[4], bv[4];
#pragma unroll
      for (int i = 0; i < 4; ++i)
        av[i] = ldsfrag128(sAh, wr * 64 + i * 16 + lrow, ksl * 4 + lg);
#pragma unroll
      for (int j = 0; j < 4; ++j)
        bv[j] = ldsfrag128(sBh, wc * 64 + j * 16 + lrow, ksl * 4 + lg);
#pragma unroll
      for (int i = 0; i < 4; ++i)
#pragma unroll
        for (int j = 0; j < 4; ++j)
          acc[i][j] = mfma16(av[i], bv[j], acc[i][j]);
    }
    __syncthreads();
  }

  unsigned short* __restrict__ C = kmode ? Ck : Cv;
#pragma unroll
  for (int i = 0; i < 4; ++i)
#pragma unroll
    for (int j = 0; j < 4; ++j)
#pragma unroll
      for (int r = 0; r < 4; ++r) {
        int row = m0 + wr * 64 + i * 16 + lg * 4 + r;
        int col = n0 + wc * 64 + j * 16 + lrow;
        C[(size_t)row * kC + col] = f2bf(acc[i][j][r]);
      }
}

// Output GEMM: out = y @ Wc^T, plain bf16, 128x64 tile, BK=128 (48KB LDS,
// grid-limited occupancy unchanged; barrier drains halve).
__global__ __launch_bounds__(256)
void gemm_out(const unsigned short* __restrict__ Yh, const unsigned short* __restrict__ Wch,
              float* __restrict__ C)
{
  __shared__ __attribute__((aligned(16))) unsigned short sAh[128 * 128];
  __shared__ __attribute__((aligned(16))) unsigned short sBh[64 * 128];
  const int bid = blockIdx.x;
  const int wg = (bid & 7) * 64 + (bid >> 3);
  const int bn = wg & 15, bm = wg >> 4;
  const int n0 = bn * 64, m0 = bm * 128;
  const int tid = threadIdx.x;
  const int w = tid >> 6, lane = tid & 63;
  const int lrow = lane & 15, lg = lane >> 4;
  const int wr = w >> 1, wc = w & 1;
  const int sr4 = w * 4 + (lane >> 4);
  const int gsh = (((lane & 15) ^ (sr4 & 7)) << 3);

  f32x4 acc[4][2];
#pragma unroll
  for (int i = 0; i < 4; ++i)
#pragma unroll
    for (int j = 0; j < 2; ++j) acc[i][j] = f32x4{0.f, 0.f, 0.f, 0.f};

  for (int k0 = 0; k0 < kC; k0 += 128) {
#pragma unroll
    for (int p = 0; p < 8; ++p) {
      const int r = p * 16 + sr4;
      const int lb = (p * 16 + w * 4) * 128;
      gload16(&Yh[(size_t)(m0 + r) * kC + k0 + gsh], &sAh[lb]);
      if (p < 4) gload16(&Wch[(size_t)(n0 + r) * kC + k0 + gsh], &sBh[lb]);
    }
    __syncthreads();
#pragma unroll
    for (int ksl = 0; ksl < 4; ++ksl) {
      bf16x8 av[4], bv[2];
#pragma unroll
      for (int i = 0; i < 4; ++i)
        av[i] = ldsfrag128(sAh, wr * 64 + i * 16 + lrow, ksl * 4 + lg);
#pragma unroll
      for (int j = 0; j < 2; ++j)
        bv[j] = ldsfrag128(sBh, wc * 32 + j * 16 + lrow, ksl * 4 + lg);
#pragma unroll
      for (int i = 0; i < 4; ++i)
#pragma unroll
        for (int j = 0; j < 2; ++j)
          acc[i][j] = mfma16(av[i], bv[j], acc[i][j]);
    }
    __syncthreads();
  }
#pragma unroll
  for (int i = 0; i < 4; ++i)
#pragma unroll
    for (int j = 0; j < 2; ++j)
#pragma unroll
      for (int r = 0; r < 4; ++r) {
        int row = m0 + wr * 64 + i * 16 + lg * 4 + r;
        int col = n0 + wc * 32 + j * 16 + lrow;
        C[(size_t)row * kC + col] = acc[i][j][r];
      }
}

// Merged post-projection pass (one dispatch, 1536 blocks x 256):
//   blocks [0,1024)    : v blend + normalize + scale -> TRANSPOSED bf16 [b,h,d,t]
//   blocks [1024,1536) : fused decay scan (4 chunk-units per block, 1/wave)
// Inputs are bf16 (kraw16/vraw16). k scale carries sqrt(log2 e).
__global__ __launch_bounds__(256)
void post_kv(const unsigned short* __restrict__ vraw16, unsigned short* __restrict__ vtbf,
             const float* __restrict__ vcf, const float* __restrict__ vsc,
             const unsigned short* __restrict__ kraw16, const float* __restrict__ lkb,
             const float* __restrict__ ksc, unsigned short* __restrict__ kbf)
{
  const int bid = blockIdx.x;
  if (bid < 1024) {
    // ---- v blend + norm + transpose ----
    __shared__ __attribute__((aligned(16))) unsigned short Ts[64][72];
    const int nt = kT / 64;              // 32
    const int t0 = (bid % nt) * 64;
    const int h = (bid / nt) % kNH;
    const int b = bid / (nt * kNH);
    const int w = threadIdx.x >> 6, lane = threadIdx.x & 63;   // lane = d
    const float vc = vcf[h];
    const float sc = __expf(kES * vsc[h]);
    size_t idx = rowoff(b, t0 + w * 16) + h * kHS + lane;
    float cur = bf2f(vraw16[idx]);
#pragma unroll
    for (int i = 0; i < 16; ++i) {
      int t = t0 + w * 16 + i;
      float nxt = (t + 1 < kT) ? bf2f(vraw16[idx + kC]) : 0.f;
      float v = (1.f - vc) * nxt + vc * cur;
      float sq = v * v;
#pragma unroll
      for (int o = 1; o < 64; o <<= 1) sq += __shfl_xor(sq, o, 64);
      Ts[w * 16 + i][lane] = f2bf(v / (sqrtf(sq) + 1e-10f) * sc);
      cur = nxt;
      idx += kC;
    }
    __syncthreads();
    const int d = threadIdx.x >> 2, tc = (threadIdx.x & 3) * 16;
    us8 o0, o1;
#pragma unroll
    for (int i = 0; i < 8; ++i) o0[i] = Ts[tc + i][d];
#pragma unroll
    for (int i = 0; i < 8; ++i) o1[i] = Ts[tc + 8 + i][d];
    size_t vo = ((size_t)(b * kNH + h) * kHS + d) * kT + t0 + tc;
    *(us8*)&vtbf[vo] = o0;
    *(us8*)&vtbf[vo + 8] = o1;
  } else {
    // ---- fused decay scan + norm ----
    const int w = threadIdx.x >> 6;
    const int d = threadIdx.x & 63;
    const int unit = (bid - 1024) * 4 + w;         // 0..2047
    const int ch = unit % kNChunk;
    const int h = (unit / kNChunk) % kNH;
    const int b = unit / (kNChunk * kNH);
    const float lam = __expf(-fabsf(lkb[h]) * kES);
    const float kscale = __expf(fminf(kES * ksc[h], kKSM)) * kSqrtLog2e;

    float cprev = 0.f;
    if (ch > 0) {   // wave-uniform branch: scan previous chunk for the carry
      float s = 0.f;
      size_t idx = rowoff(b, (ch - 1) * kChunk) + h * kHS + d;
      for (int j = 0; j < kChunk; ++j) {
        s = bf2f(kraw16[idx]) + lam * s;
        idx += kC;
      }
      cprev = s;
    }

    float s = 0.f, lpow = 1.f;
    size_t idx = rowoff(b, ch * kChunk) + h * kHS + d;
    size_t ko = ((size_t)(b * kNH + h) * kT + ch * kChunk) * kHS + d;
    for (int j = 0; j < kChunk; ++j) {
      s = bf2f(kraw16[idx]) + lam * s;   // local prefix
      lpow *= lam;
      float v = s + lpow * cprev;
      float sq = v * v;
#pragma unroll
      for (int o = 1; o < 64; o <<= 1) sq += __shfl_xor(sq, o, 64);
      kbf[ko] = f2bf(v / (sqrtf(sq) + 1e-10f) * kscale);
      idx += kC;
      ko += kHS;
    }
  }
}

// MFMA flash attention (round-16 structure, proven 44.5 us): swapped-QK^T +
// fixed-shift softmax + XCD-local LPT; K AND V double-buffered in LDS;
// K staged sigma-permuted (each lane's 16 exp'd scores ARE its PV
// A-fragment); p = 2^s via hardware exp2; P packed via v_cvt_pk_bf16_f32.
// sigma: [k5 k2 k4 k3 k1 k0]. Three structural alternatives measured worse
// (R10 fewer-blocks 61us, R12 no-LDS 145us, R17 V-direct 84us) — this
// structure is final; floor = LDS pipe + barrier drain.
__global__ __launch_bounds__(256)
void attn_mfma(const unsigned short* __restrict__ kbf,
               const unsigned short* __restrict__ vtbf,
               unsigned short* __restrict__ Yhi)
{
  constexpr int LD = 72;
  __shared__ __attribute__((aligned(16))) unsigned short Ks[2][64 * LD];
  __shared__ __attribute__((aligned(16))) unsigned short Vs[2][64 * LD];
  const int f = blockIdx.x;            // 0..1023
  const int xcd = f & 7;
  const int g = f >> 3;
  const int bh = xcd * 4 + (g & 3);    // 4 (b,h) per XCD -> K/V L2-resident
  const int qt = 31 - (g >> 2);        // LPT: biggest q-tiles first
  const int b = bh >> 4, h = bh & 15;
  const int tid = threadIdx.x;
  const int w = tid >> 6, lane = tid & 63;
  const int lrow = lane & 15, lg = lane >> 4, lk = lg * 8;
  const size_t kbase = (size_t)bh * kT * kHS;   // [t][d]
  const size_t vbase = (size_t)bh * kHS * kT;   // [d][t]
  const int srow = tid >> 2, scs = (tid & 3) * 16;
  // sigma(srow): which LDS row physical key `srow` lands in
  const int sig = (srow & 32) | ((srow & 4) << 2) | ((srow & 24) >> 1) | (srow & 3);
  const int P0 = qt * 64;

  bf16x8 qf0, qf1;
  {
    size_t qoff = kbase + (size_t)(P0 + w * 16 + lrow) * kHS + lk;
    qf0 = *(const bf16x8*)&kbf[qoff];
    qf1 = *(const bf16x8*)&kbf[qoff + 32];
  }

  f32x4 yac[4];
#pragma unroll
  for (int dt = 0; dt < 4; ++dt) yac[dt] = f32x4{0.f, 0.f, 0.f, 0.f};
  float lacc = 0.f;

  us8 nk0, nk1, nv0, nv1;
  {
    size_t gk = kbase + (size_t)srow * kHS + scs;
    nk0 = *(const us8*)&kbf[gk];
    nk1 = *(const us8*)&kbf[gk + 8];
    size_t gv = vbase + (size_t)srow * kT + scs;
    nv0 = *(const us8*)&vtbf[gv];
    nv1 = *(const us8*)&vtbf[gv + 8];
  }
  *(us8*)&Ks[0][sig * LD + scs] = nk0;
  *(us8*)&Ks[0][sig * LD + scs + 8] = nk1;
  *(us8*)&Vs[0][srow * LD + scs] = nv0;
  *(us8*)&Vs[0][srow * LD + scs + 8] = nv1;
  __syncthreads();

  int cur = 0;
  for (int j0 = 0; j0 <= P0; j0 += 64) {
    const bool more = (j0 + 64 <= P0);
    if (more) {
      size_t gk = kbase + (size_t)(j0 + 64 + srow) * kHS + scs;
      nk0 = *(const us8*)&kbf[gk];
      nk1 = *(const us8*)&kbf[gk + 8];
      size_t gv = vbase + (size_t)srow * kT + j0 + 64 + scs;
      nv0 = *(const us8*)&vtbf[gv];
      nv1 = *(const us8*)&vtbf[gv + 8];
    }

    // S^T = K Q^T (K rows sigma-permuted), acc pre-loaded with -7.5*log2e.
    // Lane (lg,lrow): s[kt][r] = log2e*(score - 7.5) for
    // key = (kt>>1)*32 + 8lg + (kt&1)*4 + r, query = lrow.
    f32x4 s[4];
    __builtin_amdgcn_s_setprio(1);
#pragma unroll
    for (int kt = 0; kt < 4; ++kt) {
      bf16x8 a0 = *(const bf16x8*)&Ks[cur][(kt * 16 + lrow) * LD + lk];
      bf16x8 a1 = *(const bf16x8*)&Ks[cur][(kt * 16 + lrow) * LD + lk + 32];
      f32x4 z = f32x4{kC4, kC4, kC4, kC4};
      z = mfma16(a0, qf0, z);
      z = mfma16(a1, qf1, z);
      s[kt] = z;
    }
    __builtin_amdgcn_s_setprio(0);

    // softmax numerator p = 2^s (hardware exp2); mask only on diagonal tile
    const int qg = P0 + w * 16 + lrow;   // this lane's query row
    float p[4][4];
    float psum = 0.f;
#pragma unroll
    for (int kt = 0; kt < 4; ++kt)
#pragma unroll
      for (int r = 0; r < 4; ++r) {
        float pv = __builtin_amdgcn_exp2f(s[kt][r]);
        if (j0 == P0) {
          int kg = j0 + (kt >> 1) * 32 + 8 * lg + ((kt & 1) << 2) + r;
          if (kg >= qg) pv = 0.f;
        }
        psum += pv;
        p[kt][r] = pv;
      }
    lacc += psum;

    // PA fragments built fully in-register (keys lg*8+j in slot order)
    union { int i[4]; bf16x8 v; } pa0u, pa1u;
    pa0u.i[0] = cvtpk(p[0][0], p[0][1]);
    pa0u.i[1] = cvtpk(p[0][2], p[0][3]);
    pa0u.i[2] = cvtpk(p[1][0], p[1][1]);
    pa0u.i[3] = cvtpk(p[1][2], p[1][3]);
    pa1u.i[0] = cvtpk(p[2][0], p[2][1]);
    pa1u.i[1] = cvtpk(p[2][2], p[2][3]);
    pa1u.i[2] = cvtpk(p[3][0], p[3][1]);
    pa1u.i[3] = cvtpk(p[3][2], p[3][3]);

    __builtin_amdgcn_s_setprio(1);
#pragma unroll
    for (int dt = 0; dt < 4; ++dt) {
      bf16x8 v0 = *(const bf16x8*)&Vs[cur][(dt * 16 + lrow) * LD + lk];
      bf16x8 v1 = *(const bf16x8*)&Vs[cur][(dt * 16 + lrow) * LD + lk + 32];
      yac[dt] = mfma16(pa0u.v, v0, yac[dt]);
      yac[dt] = mfma16(pa1u.v, v1, yac[dt]);
    }
    __builtin_amdgcn_s_setprio(0);

    if (more) {
      *(us8*)&Ks[cur ^ 1][sig * LD + scs] = nk0;
      *(us8*)&Ks[cur ^ 1][sig * LD + scs + 8] = nk1;
      *(us8*)&Vs[cur ^ 1][srow * LD + scs] = nv0;
      *(us8*)&Vs[cur ^ 1][srow * LD + scs + 8] = nv1;
    }
    __syncthreads();
    cur ^= 1;
  }

  lacc += __shfl_xor(lacc, 16, 64);
  lacc += __shfl_xor(lacc, 32, 64);
#pragma unroll
  for (int r = 0; r < 4; ++r) {
    float lq = __shfl(lacc, (lane & 48) | (lg * 4 + r), 64);
    int qg = P0 + w * 16 + lg * 4 + r;
    float inv = (qg >= 1) ? 1.f / lq : 0.f;
    size_t o = ((size_t)b * kT + qg) * kC + h * kHS;
#pragma unroll
    for (int dt = 0; dt < 4; ++dt)
      Yhi[o + dt * 16 + lrow] = f2bf(yac[dt][r] * inv);
  }
}

}  // namespace

extern "C" void kernel_launch(void* const* d_in, const int* in_sizes, int n_in,
                              void* d_out, int out_size, void* d_ws, size_t ws_size,
                              hipStream_t stream)
{
  const float* x   = (const float*)d_in[0];
  const float* Wk  = (const float*)d_in[1];
  const float* Wv  = (const float*)d_in[2];
  const float* Wc  = (const float*)d_in[3];
  const float* lkb = (const float*)d_in[4];
  const float* ksc = (const float*)d_in[5];
  const float* vcf = (const float*)d_in[6];
  const float* vsc = (const float*)d_in[7];
  float* out = (float*)d_out;

  // Workspace map (time-multiplexed):
  float* wsf = (float*)d_ws;
  unsigned short* vraw16 = (unsigned short*)wsf;   // 4,194,304 shorts — raw v bf16
  unsigned short* shA = (unsigned short*)(wsf + 4325376);  // 8,388,608 shorts region
  unsigned short* Xhi = shA;                       // phase 1: x bf16
  unsigned short* kbf  = shA;                      // phase 2: bf16 k [b,h,t,d]
  unsigned short* vtbf = shA + 4194304;            //          bf16 v^T [b,h,d,t]
  unsigned short* Wkh = (unsigned short*)(wsf + 8519680); // 3 x 1,048,576 shorts
  unsigned short* Wvh = Wkh + 1048576;
  unsigned short* Wch = Wvh + 1048576;
  unsigned short* Yhi = (unsigned short*)wsf;      // phase 3: y bf16 (vraw16 dead)
  unsigned short* kraw16 = (unsigned short*)out;   // d_out hosts bf16 k_raw
                                                   // until final GEMM overwrites

  // all splits in one dispatch (all plain bf16)
  split_all<<<7168, 256, 0, stream>>>(x, Xhi, Wk, Wkh, Wv, Wvh, Wc, Wch);

  // fused k + v projection GEMM (bf16 in, bf16 out, BK=128)
  gemm_kv<<<512, 256, 0, stream>>>(Xhi, Wkh, Wvh, kraw16, vraw16);

  // merged decay scan + v blend/norm/transpose (kbf overwrites Xhi)
  post_kv<<<1536, 256, 0, stream>>>(vraw16, vtbf, vcf, vsc, kraw16, lkb, ksc, kbf);

  // flash attention: reads kbf/vtbf, writes Yhi (vraw16 region, now dead)
  attn_mfma<<<1024, 256, 0, stream>>>(kbf, vtbf, Yhi);

  // out = y @ Wc^T  (plain bf16, BK=128)
  gemm_out<<<512, 256, 0, stream>>>(Yhi, Wch, out);
}